// Round 1
// baseline (9800.174 us; speedup 1.0000x reference)
//
#include <hip/hip_runtime.h>
#include <math.h>

#define HH 512
#define VV 32000
#define BB 64
#define SS 64
#define TT 64
#define H3 1536

// workspace layout (floats)
#define WS_UK    0LL
#define WS_GIEMB (WS_UK + (long long)BB*SS*HH)        // Uk:    B*S*H
#define WS_HS    (WS_GIEMB + (long long)TT*BB*H3)     // GiEmb: T*B*3H
#define WS_QGH   (WS_HS + (long long)TT*BB*HH)        // Hs:    T*B*H
#define WS_CTX   (WS_QGH + (long long)BB*2048)        // qgh:   B*2048 (q | gh)
#define WS_GIC   (WS_CTX + (long long)BB*HH)          // ctx:   B*H
#define WS_WCAT  (WS_GIC + (long long)BB*H3)          // gic:   B*3H
#define WS_BCAT  (WS_WCAT + 2048LL*HH)                // Wcat:  2048*H
// total = WS_BCAT + 2048 floats  (~47.2 MB)

// output layout (floats)
#define OUT_HT  ((long long)BB*TT*VV)
#define OUT_ATT (OUT_HT + (long long)BB*HH)

// ---------------------------------------------------------------------------
// Generic NT GEMM: C[m,n] = sum_k Arow(m)[k] * Bm[n*ldb + k] + bias[n]
// K is fixed at 512. BM=BN=64, BK=16, 256 threads, 4x4 micro-tile.
// ROWMAP: 0 = A row m;  1 = emb gather (m = t*B+b, tok from target);
//         2 = Hs permute (m = b*T+t -> row t*B+b)
// ---------------------------------------------------------------------------
template<int ROWMAP>
__global__ __launch_bounds__(256) void gemm_nt(const float* __restrict__ A, int lda,
    const float* __restrict__ Bm, int ldb, const float* __restrict__ bias,
    float* __restrict__ C, long long ldc, const int* __restrict__ tok)
{
  __shared__ float As[16][68];
  __shared__ float Bs[16][68];
  const int tid = threadIdx.x;
  const int tx = tid & 15, ty = tid >> 4;
  const int lr = tid & 63, lc = (tid >> 6) << 2;   // loader: row-in-tile, k-offset
  const int m0 = blockIdx.y * 64, n0 = blockIdx.x * 64;

  long long arow;
  {
    int m = m0 + lr;
    if (ROWMAP == 0) {
      arow = (long long)m * lda;
    } else if (ROWMAP == 1) {
      int t = m >> 6, b = m & 63;
      int tk = (t == 0) ? 0 : tok[b * TT + t - 1];
      arow = (long long)tk * lda;
    } else {
      int t = m & 63, b = m >> 6;
      arow = (long long)(t * BB + b) * lda;
    }
  }
  const float* Ap = A + arow;
  const float* Bp = Bm + (long long)(n0 + lr) * ldb;

  float acc[4][4];
  #pragma unroll
  for (int i = 0; i < 4; i++)
    #pragma unroll
    for (int j = 0; j < 4; j++) acc[i][j] = 0.f;

  for (int k0 = 0; k0 < HH; k0 += 16) {
    float4 av = *(const float4*)(Ap + k0 + lc);
    float4 bv = *(const float4*)(Bp + k0 + lc);
    __syncthreads();
    As[lc+0][lr] = av.x; As[lc+1][lr] = av.y; As[lc+2][lr] = av.z; As[lc+3][lr] = av.w;
    Bs[lc+0][lr] = bv.x; Bs[lc+1][lr] = bv.y; Bs[lc+2][lr] = bv.z; Bs[lc+3][lr] = bv.w;
    __syncthreads();
    #pragma unroll
    for (int kk = 0; kk < 16; kk++) {
      float a[4], b[4];
      #pragma unroll
      for (int i = 0; i < 4; i++) a[i] = As[kk][i*16 + ty];
      #pragma unroll
      for (int j = 0; j < 4; j++) b[j] = Bs[kk][j*16 + tx];
      #pragma unroll
      for (int i = 0; i < 4; i++)
        #pragma unroll
        for (int j = 0; j < 4; j++) acc[i][j] += a[i] * b[j];
    }
  }

  #pragma unroll
  for (int j = 0; j < 4; j++) {
    int col = n0 + j*16 + tx;
    float bb = bias ? bias[col] : 0.f;
    #pragma unroll
    for (int i = 0; i < 4; i++) {
      int row = m0 + i*16 + ty;
      C[(long long)row * ldc + col] = acc[i][j] + bb;
    }
  }
}

// ---------------------------------------------------------------------------
// One-time concat: Wcat = [Wa ; W_hh] (2048 x 512), bcat = [ba ; b_hh]
// ---------------------------------------------------------------------------
__global__ __launch_bounds__(256) void wcat_kernel(const float* __restrict__ Wa,
    const float* __restrict__ Whh, const float* __restrict__ ba,
    const float* __restrict__ bhh, float* __restrict__ Wcat, float* __restrict__ bcat)
{
  long long i = (long long)blockIdx.x * 256 + threadIdx.x;   // grid 4096 -> 1,048,576 threads
  int j = (int)(i >> 9), k = (int)(i & 511);
  Wcat[i] = (j < HH) ? Wa[(long long)j*HH + k] : Whh[(long long)(j - HH)*HH + k];
  if (i < 2048) bcat[i] = (i < HH) ? ba[i] : bhh[i - HH];
}

// ---------------------------------------------------------------------------
// Attention for step t: per-b block. Reads q (cols 0..511 of qgh), Uk, Va.
// Writes softmax weights to out attentions[b][t][:] and ctx[b][:].
// ---------------------------------------------------------------------------
__global__ __launch_bounds__(256) void attn_kernel(const float* __restrict__ qgh,
    const float* __restrict__ Uk, const float* __restrict__ Va,
    const float* __restrict__ bvp, const float* __restrict__ enc,
    float* __restrict__ ctx, float* __restrict__ attn_out, int t)
{
  const int b = blockIdx.x, tid = threadIdx.x;
  __shared__ __align__(16) float qs[HH];
  __shared__ float sw[SS];
  qs[tid]       = qgh[(long long)b*2048 + tid];
  qs[tid + 256] = qgh[(long long)b*2048 + tid + 256];
  __syncthreads();

  // scores[b,s] = bv + sum_k Va[k] * tanh(q[b,k] + Uk[b,s,k]); 4 threads per s
  const int s = tid >> 2, qq = tid & 3;
  const float* ukp = Uk + (long long)(b*SS + s) * HH;
  float p = 0.f;
  #pragma unroll 4
  for (int it = 0; it < 32; ++it) {
    int k = qq*4 + it*16;
    float4 u4 = *(const float4*)(ukp + k);
    float4 q4 = *(const float4*)(qs + k);
    float4 v4 = *(const float4*)(Va + k);
    p += v4.x * tanhf(q4.x + u4.x) + v4.y * tanhf(q4.y + u4.y)
       + v4.z * tanhf(q4.z + u4.z) + v4.w * tanhf(q4.w + u4.w);
  }
  p += __shfl_xor(p, 1);
  p += __shfl_xor(p, 2);
  if (qq == 0) sw[s] = p + bvp[0];
  __syncthreads();

  // softmax over S=64 in wave 0
  if (tid < 64) {
    float x = sw[tid], mx = x;
    #pragma unroll
    for (int off = 32; off; off >>= 1) mx = fmaxf(mx, __shfl_xor(mx, off));
    float e = expf(x - mx), sm = e;
    #pragma unroll
    for (int off = 32; off; off >>= 1) sm += __shfl_xor(sm, off);
    float w = e / sm;
    sw[tid] = w;
    attn_out[(long long)b*TT*SS + (long long)t*SS + tid] = w;
  }
  __syncthreads();

  // ctx[b,h] = sum_s w[s] * enc[b,s,h]
  float a0 = 0.f, a1 = 0.f;
  for (int s2 = 0; s2 < SS; ++s2) {
    float w = sw[s2];
    const float* ep = enc + (long long)(b*SS + s2) * HH;
    a0 += w * ep[tid];
    a1 += w * ep[tid + 256];
  }
  ctx[b*HH + tid]       = a0;
  ctx[b*HH + tid + 256] = a1;
}

// ---------------------------------------------------------------------------
// GRU gates + state update for step t. gi = GiEmb + gic, gh from qgh cols 512+.
// ---------------------------------------------------------------------------
__global__ __launch_bounds__(256) void gates_kernel(const float* __restrict__ giemb,
    const float* __restrict__ gic, const float* __restrict__ qgh,
    const float* __restrict__ hprev, float* __restrict__ hnew,
    float* __restrict__ ht_out, int t)
{
  const int b = blockIdx.x, tid = threadIdx.x;
  const long long gie = (long long)(t*BB + b) * H3;
  const float* ghp = qgh + (long long)b*2048 + HH;
  #pragma unroll
  for (int u = 0; u < 2; ++u) {
    int j = tid + u*256;
    float gi_r = giemb[gie + j]        + gic[(long long)b*H3 + j];
    float gi_z = giemb[gie + HH + j]   + gic[(long long)b*H3 + HH + j];
    float gi_n = giemb[gie + 2*HH + j] + gic[(long long)b*H3 + 2*HH + j];
    float gh_r = ghp[j], gh_z = ghp[HH + j], gh_n = ghp[2*HH + j];
    float r = 1.f / (1.f + expf(-(gi_r + gh_r)));
    float z = 1.f / (1.f + expf(-(gi_z + gh_z)));
    float n = tanhf(gi_n + r * gh_n);
    float hp = hprev[(long long)b*HH + j];
    float hn = (1.f - z) * n + z * hp;
    hnew[(long long)b*HH + j] = hn;
    if (ht_out) ht_out[(long long)b*HH + j] = hn;
  }
}

// ---------------------------------------------------------------------------
// In-place log-softmax over rows of V=32000 (one block per row), online LSE.
// ---------------------------------------------------------------------------
__global__ __launch_bounds__(256) void logsoftmax_kernel(float* __restrict__ lp)
{
  float* p = lp + (long long)blockIdx.x * VV;
  const int tid = threadIdx.x;
  float m = -1e30f, s = 0.f;
  for (int v = tid; v < VV; v += 256) {
    float x = p[v];
    if (x > m) { s = s * expf(m - x) + 1.f; m = x; }
    else       { s += expf(x - m); }
  }
  __shared__ float rm[256], rs[256];
  rm[tid] = m; rs[tid] = s;
  __syncthreads();
  for (int off = 128; off; off >>= 1) {
    if (tid < off) {
      float m2 = rm[tid + off], s2 = rs[tid + off];
      float mm = fmaxf(rm[tid], m2);
      rs[tid] = rs[tid] * expf(rm[tid] - mm) + s2 * expf(m2 - mm);
      rm[tid] = mm;
    }
    __syncthreads();
  }
  const float L = rm[0] + logf(rs[0]);
  for (int v = tid; v < VV; v += 256) p[v] -= L;
}

// ---------------------------------------------------------------------------
extern "C" void kernel_launch(void* const* d_in, const int* in_sizes, int n_in,
                              void* d_out, int out_size, void* d_ws, size_t ws_size,
                              hipStream_t stream)
{
  const float* enc   = (const float*)d_in[0];
  const float* eh    = (const float*)d_in[1];
  const int*   tgt   = (const int*)  d_in[2];
  const float* emb   = (const float*)d_in[3];
  const float* Wa    = (const float*)d_in[4];
  const float* ba    = (const float*)d_in[5];
  const float* Ua    = (const float*)d_in[6];
  const float* bu    = (const float*)d_in[7];
  const float* Va    = (const float*)d_in[8];
  const float* bvp   = (const float*)d_in[9];
  const float* W_ih  = (const float*)d_in[10];
  const float* W_hh  = (const float*)d_in[11];
  const float* b_ih  = (const float*)d_in[12];
  const float* b_hh  = (const float*)d_in[13];
  const float* W_out = (const float*)d_in[14];
  const float* b_out = (const float*)d_in[15];

  float* out = (float*)d_out;
  float* ws  = (float*)d_ws;

  float* uk   = ws + WS_UK;
  float* gie  = ws + WS_GIEMB;
  float* hs   = ws + WS_HS;
  float* qgh  = ws + WS_QGH;
  float* ctx  = ws + WS_CTX;
  float* gic  = ws + WS_GIC;
  float* wcat = ws + WS_WCAT;
  float* bcat = ws + WS_BCAT;

  // one-time weight concat [Wa ; W_hh]
  wcat_kernel<<<dim3(4096), dim3(256), 0, stream>>>(Wa, W_hh, ba, b_hh, wcat, bcat);

  // Uk[b,s,k] = enc[b,s,:] . Ua[k,:] + bu[k]       (M=4096, N=512)
  gemm_nt<0><<<dim3(8, 64), dim3(256), 0, stream>>>(enc, HH, Ua, HH, bu, uk, (long long)HH, nullptr);

  // GiEmb[t,b,j] = emb[tok[b,t]] . W_ih[j, 0:H] + b_ih[j]   (M=4096, N=1536)
  gemm_nt<1><<<dim3(24, 64), dim3(256), 0, stream>>>(emb, HH, W_ih, 2*HH, b_ih, gie, (long long)H3, tgt);

  for (int t = 0; t < TT; ++t) {
    const float* hprev = (t == 0) ? eh : (hs + (long long)(t - 1) * BB * HH);
    // [q | gh] = hprev @ [Wa ; W_hh]^T + [ba ; b_hh]   (M=64, N=2048)
    gemm_nt<0><<<dim3(32, 1), dim3(256), 0, stream>>>(hprev, HH, wcat, HH, bcat, qgh, 2048LL, nullptr);
    // attention -> w (to d_out), ctx
    attn_kernel<<<dim3(64), dim3(256), 0, stream>>>(qgh, uk, Va, bvp, enc, ctx, out + OUT_ATT, t);
    // gic = ctx @ W_ih[:, H:2H]^T                     (M=64, N=1536, no bias)
    gemm_nt<0><<<dim3(24, 1), dim3(256), 0, stream>>>(ctx, HH, W_ih + HH, 2*HH, nullptr, gic, (long long)H3, nullptr);
    // gates + h update; write Hs[t]; final step also writes hT output
    gates_kernel<<<dim3(64), dim3(256), 0, stream>>>(gie, gic, qgh, hprev,
        hs + (long long)t * BB * HH, (t == TT - 1) ? (out + OUT_HT) : nullptr, t);
  }

  // logits[b*T+t, v] = Hs[t,b,:] . W_out[v,:] + b_out[v]  (M=4096, N=32000)
  gemm_nt<2><<<dim3(500, 64), dim3(256), 0, stream>>>(hs, HH, W_out, HH, b_out, out, (long long)VV, nullptr);

  // in-place log-softmax over V
  logsoftmax_kernel<<<dim3(4096), dim3(256), 0, stream>>>(out);
}

// Round 2
// 7207.638 us; speedup vs baseline: 1.3597x; 1.3597x over previous
//
#include <hip/hip_runtime.h>
#include <math.h>

#define HH 512
#define VV 32000
#define BB 64
#define SS 64
#define TT 64
#define H3 1536

// workspace layout (float offsets)
#define WS_UK    0LL
#define WS_GIEMB (WS_UK + (long long)BB*SS*HH)        // Uk:    B*S*H
#define WS_HS    (WS_GIEMB + (long long)TT*BB*H3)     // GiEmb: T*B*3H
#define WS_QGH   (WS_HS + (long long)TT*BB*HH)        // Hs:    T*B*H (fp32)
#define WS_CTX   (WS_QGH + (long long)BB*2048)        // qgh:   B*2048 (q | gh)
#define WS_GIC   (WS_CTX + (long long)BB*HH)          // ctx:   B*H
#define WS_WCAT  (WS_GIC + (long long)BB*H3)          // gic:   B*3H
#define WS_BCAT  (WS_WCAT + 2048LL*HH)                // Wcat:  2048*H
#define WS_HSBF  (WS_BCAT + 2048LL)                   // hsbf:  T*B*H bf16 (permuted rows b*T+t)
#define WS_END   (WS_HSBF + (long long)TT*BB*HH/2)
// wbf (W_out in bf16, 32000*512 shorts = 8.192M float-equiv) ALIASES ws[0..8.192M):
// it overlaps Uk+GiEmb which are dead after the recurrence; conversion runs after step 63.

// output layout (floats)
#define OUT_HT  ((long long)BB*TT*VV)
#define OUT_ATT (OUT_HT + (long long)BB*HH)

typedef __attribute__((ext_vector_type(8))) short bf16x8;
typedef __attribute__((ext_vector_type(4))) float f32x4;

__device__ inline unsigned short f2b(float x) {
  unsigned u = __builtin_bit_cast(unsigned, x);
  unsigned r = (u + 0x7FFF + ((u >> 16) & 1)) >> 16;
  return (unsigned short)r;
}

// ---------------------------------------------------------------------------
// Generic fp32 NT GEMM (kept for small/medium matmuls).
// ROWMAP: 0 = A row m;  1 = emb gather (m = t*B+b, tok from target)
// ---------------------------------------------------------------------------
template<int ROWMAP>
__global__ __launch_bounds__(256) void gemm_nt(const float* __restrict__ A, int lda,
    const float* __restrict__ Bm, int ldb, const float* __restrict__ bias,
    float* __restrict__ C, long long ldc, const int* __restrict__ tok)
{
  __shared__ float As[16][68];
  __shared__ float Bs[16][68];
  const int tid = threadIdx.x;
  const int tx = tid & 15, ty = tid >> 4;
  const int lr = tid & 63, lc = (tid >> 6) << 2;
  const int m0 = blockIdx.y * 64, n0 = blockIdx.x * 64;

  long long arow;
  {
    int m = m0 + lr;
    if (ROWMAP == 0) {
      arow = (long long)m * lda;
    } else {
      int t = m >> 6, b = m & 63;
      int tk = (t == 0) ? 0 : tok[b * TT + t - 1];
      arow = (long long)tk * lda;
    }
  }
  const float* Ap = A + arow;
  const float* Bp = Bm + (long long)(n0 + lr) * ldb;

  float acc[4][4];
  #pragma unroll
  for (int i = 0; i < 4; i++)
    #pragma unroll
    for (int j = 0; j < 4; j++) acc[i][j] = 0.f;

  for (int k0 = 0; k0 < HH; k0 += 16) {
    float4 av = *(const float4*)(Ap + k0 + lc);
    float4 bv = *(const float4*)(Bp + k0 + lc);
    __syncthreads();
    As[lc+0][lr] = av.x; As[lc+1][lr] = av.y; As[lc+2][lr] = av.z; As[lc+3][lr] = av.w;
    Bs[lc+0][lr] = bv.x; Bs[lc+1][lr] = bv.y; Bs[lc+2][lr] = bv.z; Bs[lc+3][lr] = bv.w;
    __syncthreads();
    #pragma unroll
    for (int kk = 0; kk < 16; kk++) {
      float a[4], b[4];
      #pragma unroll
      for (int i = 0; i < 4; i++) a[i] = As[kk][i*16 + ty];
      #pragma unroll
      for (int j = 0; j < 4; j++) b[j] = Bs[kk][j*16 + tx];
      #pragma unroll
      for (int i = 0; i < 4; i++)
        #pragma unroll
        for (int j = 0; j < 4; j++) acc[i][j] += a[i] * b[j];
    }
  }

  #pragma unroll
  for (int j = 0; j < 4; j++) {
    int col = n0 + j*16 + tx;
    float bb = bias ? bias[col] : 0.f;
    #pragma unroll
    for (int i = 0; i < 4; i++) {
      int row = m0 + i*16 + ty;
      C[(long long)row * ldc + col] = acc[i][j] + bb;
    }
  }
}

// ---------------------------------------------------------------------------
// One-time concat: Wcat = [Wa ; W_hh] (2048 x 512), bcat = [ba ; b_hh]
// ---------------------------------------------------------------------------
__global__ __launch_bounds__(256) void wcat_kernel(const float* __restrict__ Wa,
    const float* __restrict__ Whh, const float* __restrict__ ba,
    const float* __restrict__ bhh, float* __restrict__ Wcat, float* __restrict__ bcat)
{
  long long i = (long long)blockIdx.x * 256 + threadIdx.x;
  int j = (int)(i >> 9), k = (int)(i & 511);
  Wcat[i] = (j < HH) ? Wa[(long long)j*HH + k] : Whh[(long long)(j - HH)*HH + k];
  if (i < 2048) bcat[i] = (i < HH) ? ba[i] : bhh[i - HH];
}

// ---------------------------------------------------------------------------
// W_out (32000x512 fp32) -> bf16, 8 elems/thread
// ---------------------------------------------------------------------------
__global__ __launch_bounds__(256) void cvt_wout_kernel(const float* __restrict__ in,
    unsigned short* __restrict__ outp)
{
  long long i = ((long long)blockIdx.x * 256 + threadIdx.x) * 8;
  float4 a = *(const float4*)(in + i);
  float4 b = *(const float4*)(in + i + 4);
  ushort4 lo = { f2b(a.x), f2b(a.y), f2b(a.z), f2b(a.w) };
  ushort4 hi = { f2b(b.x), f2b(b.y), f2b(b.z), f2b(b.w) };
  *(ushort4*)(outp + i)     = lo;
  *(ushort4*)(outp + i + 4) = hi;
}

// ---------------------------------------------------------------------------
// Attention for step t (unchanged from R1)
// ---------------------------------------------------------------------------
__global__ __launch_bounds__(256) void attn_kernel(const float* __restrict__ qgh,
    const float* __restrict__ Uk, const float* __restrict__ Va,
    const float* __restrict__ bvp, const float* __restrict__ enc,
    float* __restrict__ ctx, float* __restrict__ attn_out, int t)
{
  const int b = blockIdx.x, tid = threadIdx.x;
  __shared__ __align__(16) float qs[HH];
  __shared__ float sw[SS];
  qs[tid]       = qgh[(long long)b*2048 + tid];
  qs[tid + 256] = qgh[(long long)b*2048 + tid + 256];
  __syncthreads();

  const int s = tid >> 2, qq = tid & 3;
  const float* ukp = Uk + (long long)(b*SS + s) * HH;
  float p = 0.f;
  #pragma unroll 4
  for (int it = 0; it < 32; ++it) {
    int k = qq*4 + it*16;
    float4 u4 = *(const float4*)(ukp + k);
    float4 q4 = *(const float4*)(qs + k);
    float4 v4 = *(const float4*)(Va + k);
    p += v4.x * tanhf(q4.x + u4.x) + v4.y * tanhf(q4.y + u4.y)
       + v4.z * tanhf(q4.z + u4.z) + v4.w * tanhf(q4.w + u4.w);
  }
  p += __shfl_xor(p, 1);
  p += __shfl_xor(p, 2);
  if (qq == 0) sw[s] = p + bvp[0];
  __syncthreads();

  if (tid < 64) {
    float x = sw[tid], mx = x;
    #pragma unroll
    for (int off = 32; off; off >>= 1) mx = fmaxf(mx, __shfl_xor(mx, off));
    float e = expf(x - mx), sm = e;
    #pragma unroll
    for (int off = 32; off; off >>= 1) sm += __shfl_xor(sm, off);
    float w = e / sm;
    sw[tid] = w;
    attn_out[(long long)b*TT*SS + (long long)t*SS + tid] = w;
  }
  __syncthreads();

  float a0 = 0.f, a1 = 0.f;
  for (int s2 = 0; s2 < SS; ++s2) {
    float w = sw[s2];
    const float* ep = enc + (long long)(b*SS + s2) * HH;
    a0 += w * ep[tid];
    a1 += w * ep[tid + 256];
  }
  ctx[b*HH + tid]       = a0;
  ctx[b*HH + tid + 256] = a1;
}

// ---------------------------------------------------------------------------
// GRU gates + h update; also writes bf16 h into hsbf at permuted row b*T+t
// ---------------------------------------------------------------------------
__global__ __launch_bounds__(256) void gates_kernel(const float* __restrict__ giemb,
    const float* __restrict__ gic, const float* __restrict__ qgh,
    const float* __restrict__ hprev, float* __restrict__ hnew,
    unsigned short* __restrict__ hbf, float* __restrict__ ht_out, int t)
{
  const int b = blockIdx.x, tid = threadIdx.x;
  const long long gie = (long long)(t*BB + b) * H3;
  const float* ghp = qgh + (long long)b*2048 + HH;
  #pragma unroll
  for (int u = 0; u < 2; ++u) {
    int j = tid + u*256;
    float gi_r = giemb[gie + j]        + gic[(long long)b*H3 + j];
    float gi_z = giemb[gie + HH + j]   + gic[(long long)b*H3 + HH + j];
    float gi_n = giemb[gie + 2*HH + j] + gic[(long long)b*H3 + 2*HH + j];
    float gh_r = ghp[j], gh_z = ghp[HH + j], gh_n = ghp[2*HH + j];
    float r = 1.f / (1.f + expf(-(gi_r + gh_r)));
    float z = 1.f / (1.f + expf(-(gi_z + gh_z)));
    float n = tanhf(gi_n + r * gh_n);
    float hp = hprev[(long long)b*HH + j];
    float hn = (1.f - z) * n + z * hp;
    hnew[(long long)b*HH + j] = hn;
    hbf[((long long)b*TT + t)*HH + j] = f2b(hn);
    if (ht_out) ht_out[(long long)b*HH + j] = hn;
  }
}

// ---------------------------------------------------------------------------
// Output projection: C[m, v] = hsbf[m,:] . wbf[v,:] + b_out[v]
// bf16 MFMA 16x16x32, 128x128 tile, BK=32, 4 waves (2x2), global_load_lds w16.
// M=4096 (rows are b*T+t, matching d_out), N=32000, K=512.
// ---------------------------------------------------------------------------
__global__ __launch_bounds__(256) void gemm_out_mfma(const unsigned short* __restrict__ A,
    const unsigned short* __restrict__ Bw, const float* __restrict__ bias,
    float* __restrict__ C)
{
  __shared__ unsigned short As[128*32];
  __shared__ unsigned short Bs[128*32];
  const int tid = threadIdx.x;
  const int w = tid >> 6, l = tid & 63;
  const int m0 = blockIdx.y * 128, n0 = blockIdx.x * 128;
  const int wr = w >> 1, wc = w & 1;

  f32x4 acc[4][4];
  #pragma unroll
  for (int i = 0; i < 4; i++)
    #pragma unroll
    for (int j = 0; j < 4; j++) acc[i][j] = (f32x4){0.f, 0.f, 0.f, 0.f};

  const int srow = l >> 2;          // 0..15 within 16-row group
  const int scol = (l & 3) * 8;     // bf16 offset within 32-wide row

  for (int k0 = 0; k0 < HH; k0 += 32) {
    __syncthreads();   // previous iter's reads done before overwrite
    #pragma unroll
    for (int q = 0; q < 2; ++q) {
      int r = w*32 + q*16 + srow;   // LDS row; byte off = w*2048+q*1024+l*16 (linear in lane)
      __builtin_amdgcn_global_load_lds(
          (const __attribute__((address_space(1))) void*)(A + (long long)(m0 + r)*HH + k0 + scol),
          (__attribute__((address_space(3))) void*)(As + r*32 + scol), 16, 0, 0);
      __builtin_amdgcn_global_load_lds(
          (const __attribute__((address_space(1))) void*)(Bw + (long long)(n0 + r)*HH + k0 + scol),
          (__attribute__((address_space(3))) void*)(Bs + r*32 + scol), 16, 0, 0);
    }
    __syncthreads();   // tiles visible (compiler drains vmcnt before barrier)

    bf16x8 a[4], b[4];
    #pragma unroll
    for (int mi = 0; mi < 4; mi++)
      a[mi] = *(const bf16x8*)&As[(wr*64 + mi*16 + (l & 15))*32 + (l >> 4)*8];
    #pragma unroll
    for (int ni = 0; ni < 4; ni++)
      b[ni] = *(const bf16x8*)&Bs[(wc*64 + ni*16 + (l & 15))*32 + (l >> 4)*8];
    #pragma unroll
    for (int mi = 0; mi < 4; mi++)
      #pragma unroll
      for (int ni = 0; ni < 4; ni++)
        acc[mi][ni] = __builtin_amdgcn_mfma_f32_16x16x32_bf16(a[mi], b[ni], acc[mi][ni], 0, 0, 0);
  }

  #pragma unroll
  for (int mi = 0; mi < 4; mi++) {
    #pragma unroll
    for (int ni = 0; ni < 4; ni++) {
      int col = n0 + wc*64 + ni*16 + (l & 15);
      float bb = bias[col];
      #pragma unroll
      for (int r2 = 0; r2 < 4; r2++) {
        int row = m0 + wr*64 + mi*16 + (l >> 4)*4 + r2;
        C[(long long)row*VV + col] = acc[mi][ni][r2] + bb;
      }
    }
  }
}

// ---------------------------------------------------------------------------
// In-place log-softmax over rows of V=32000 (one block per row), online LSE.
// ---------------------------------------------------------------------------
__global__ __launch_bounds__(256) void logsoftmax_kernel(float* __restrict__ lp)
{
  float* p = lp + (long long)blockIdx.x * VV;
  const int tid = threadIdx.x;
  float m = -1e30f, s = 0.f;
  for (int v = tid; v < VV; v += 256) {
    float x = p[v];
    if (x > m) { s = s * expf(m - x) + 1.f; m = x; }
    else       { s += expf(x - m); }
  }
  __shared__ float rm[256], rs[256];
  rm[tid] = m; rs[tid] = s;
  __syncthreads();
  for (int off = 128; off; off >>= 1) {
    if (tid < off) {
      float m2 = rm[tid + off], s2 = rs[tid + off];
      float mm = fmaxf(rm[tid], m2);
      rs[tid] = rs[tid] * expf(rm[tid] - mm) + s2 * expf(m2 - mm);
      rm[tid] = mm;
    }
    __syncthreads();
  }
  const float L = rm[0] + logf(rs[0]);
  for (int v = tid; v < VV; v += 256) p[v] -= L;
}

// ---------------------------------------------------------------------------
extern "C" void kernel_launch(void* const* d_in, const int* in_sizes, int n_in,
                              void* d_out, int out_size, void* d_ws, size_t ws_size,
                              hipStream_t stream)
{
  const float* enc   = (const float*)d_in[0];
  const float* eh    = (const float*)d_in[1];
  const int*   tgt   = (const int*)  d_in[2];
  const float* emb   = (const float*)d_in[3];
  const float* Wa    = (const float*)d_in[4];
  const float* ba    = (const float*)d_in[5];
  const float* Ua    = (const float*)d_in[6];
  const float* bu    = (const float*)d_in[7];
  const float* Va    = (const float*)d_in[8];
  const float* bvp   = (const float*)d_in[9];
  const float* W_ih  = (const float*)d_in[10];
  const float* W_hh  = (const float*)d_in[11];
  const float* b_ih  = (const float*)d_in[12];
  const float* b_hh  = (const float*)d_in[13];
  const float* W_out = (const float*)d_in[14];
  const float* b_out = (const float*)d_in[15];

  float* out = (float*)d_out;
  float* ws  = (float*)d_ws;

  float* uk   = ws + WS_UK;
  float* gie  = ws + WS_GIEMB;
  float* hs   = ws + WS_HS;
  float* qgh  = ws + WS_QGH;
  float* ctx  = ws + WS_CTX;
  float* gic  = ws + WS_GIC;
  float* wcat = ws + WS_WCAT;
  float* bcat = ws + WS_BCAT;
  unsigned short* hsbf = (unsigned short*)(ws + WS_HSBF);
  unsigned short* wbf  = (unsigned short*)ws;   // aliases Uk+GiEmb (dead after recurrence)

  wcat_kernel<<<dim3(4096), dim3(256), 0, stream>>>(Wa, W_hh, ba, b_hh, wcat, bcat);

  // Uk[b,s,k] = enc[b,s,:] . Ua[k,:] + bu[k]
  gemm_nt<0><<<dim3(8, 64), dim3(256), 0, stream>>>(enc, HH, Ua, HH, bu, uk, (long long)HH, nullptr);

  // GiEmb[t,b,j] = emb[tok[b,t]] . W_ih[j, 0:H] + b_ih[j]
  gemm_nt<1><<<dim3(24, 64), dim3(256), 0, stream>>>(emb, HH, W_ih, 2*HH, b_ih, gie, (long long)H3, tgt);

  for (int t = 0; t < TT; ++t) {
    const float* hprev = (t == 0) ? eh : (hs + (long long)(t - 1) * BB * HH);
    gemm_nt<0><<<dim3(32, 1), dim3(256), 0, stream>>>(hprev, HH, wcat, HH, bcat, qgh, 2048LL, nullptr);
    attn_kernel<<<dim3(64), dim3(256), 0, stream>>>(qgh, uk, Va, bvp, enc, ctx, out + OUT_ATT, t);
    gemm_nt<0><<<dim3(24, 1), dim3(256), 0, stream>>>(ctx, HH, W_ih + HH, 2*HH, nullptr, gic, (long long)H3, nullptr);
    gates_kernel<<<dim3(64), dim3(256), 0, stream>>>(gie, gic, qgh, hprev,
        hs + (long long)t * BB * HH, hsbf, (t == TT - 1) ? (out + OUT_HT) : nullptr, t);
  }

  // W_out -> bf16 (into dead Uk/GiEmb region), AFTER recurrence
  cvt_wout_kernel<<<dim3(8000), dim3(256), 0, stream>>>(W_out, wbf);

  // logits = hsbf @ wbf^T + b_out  (MFMA)
  gemm_out_mfma<<<dim3(250, 32), dim3(256), 0, stream>>>(hsbf, wbf, b_out, out);

  // in-place log-softmax over V
  logsoftmax_kernel<<<dim3(4096), dim3(256), 0, stream>>>(out);
}